// Round 1
// baseline (1451.300 us; speedup 1.0000x reference)
//
#include <hip/hip_runtime.h>
#include <hip/hip_bf16.h>

#define N_USERS 50000
#define N_ITEMS 4000
#define BATCH   256
#define KSTEPS  125            // 4000 / 32
#define NWG     391            // ceil(50000 / 128)
#define NEG_INF (-3.402823466e38f)

typedef __attribute__((ext_vector_type(8)))  __bf16 bfrag;
typedef __attribute__((ext_vector_type(16))) float  f32x16;

__device__ __forceinline__ unsigned short f2bf(float f) {
  unsigned u = __float_as_uint(f);
  return (unsigned short)((u + 0x7FFFu + ((u >> 16) & 1u)) >> 16);  // RNE
}

// ---------------- Kernel 1: gather user rows, convert bf16, pack [kstep][256][32]
__global__ __launch_bounds__(256) void prep_pack(
    const float* __restrict__ F, const int* __restrict__ uids,
    unsigned short* __restrict__ apack) {
  int m = blockIdx.x;
  size_t base = (size_t)uids[m] * N_ITEMS;
  for (int kk = threadIdx.x * 4; kk < N_ITEMS; kk += 1024) {
    float4 v = *(const float4*)(F + base + kk);
    ushort4 o;
    o.x = f2bf(v.x); o.y = f2bf(v.y); o.z = f2bf(v.z); o.w = f2bf(v.w);
    *(ushort4*)(apack + (size_t)(kk >> 5) * 8192 + m * 32 + (kk & 31)) = o;
  }
}

// ---------------- Kernel 2: fused GEMM (256x128 tile) + norm_all + per-WG top-8 per row
__global__ __launch_bounds__(256, 2) void gemm_topk(
    const float* __restrict__ F, const unsigned short* __restrict__ apack,
    float2* __restrict__ wstop) {
  union Smem {
    struct { unsigned short As[256][40]; unsigned short Bs[128][40]; } g;  // 40: pad for banks+16B align
    float dump[4][64][33];
  };
  __shared__ Smem sm;
  __shared__ float norms[128];

  const int tid  = threadIdx.x;
  const int w    = tid >> 6, lane = tid & 63;
  const int lrow = lane & 31, lhalf = lane >> 5;
  const int n0   = blockIdx.x * 128;

  // staging assignment (fixed per thread): A row=tid; B row=tid>>1, half=tid&1
  const uint4* aptr = (const uint4*)apack + tid * 4;
  const int brow = tid >> 1, bh = tid & 1;
  const bool bvalid = (n0 + brow) < N_USERS;
  const float4* bptr = (const float4*)(F + (size_t)(bvalid ? (n0 + brow) : 0) * N_ITEMS) + bh * 4;

  f32x16 acc[2][4];
  #pragma unroll
  for (int i = 0; i < 2; ++i)
    #pragma unroll
    for (int j = 0; j < 4; ++j)
      #pragma unroll
      for (int e = 0; e < 16; ++e) acc[i][j][e] = 0.f;

  float ssq = 0.f;
  uint4 ar[4]; float4 br[4];

  { // prologue: load kstep 0
    ar[0] = aptr[0]; ar[1] = aptr[1]; ar[2] = aptr[2]; ar[3] = aptr[3];
    if (bvalid) { br[0] = bptr[0]; br[1] = bptr[1]; br[2] = bptr[2]; br[3] = bptr[3]; }
    else { br[0] = br[1] = br[2] = br[3] = make_float4(0.f, 0.f, 0.f, 0.f); }
  }

  for (int ks = 0; ks < KSTEPS; ++ks) {
    if (ks) __syncthreads();
    // stage A (bf16 already)
    uint4* adst = (uint4*)&sm.g.As[tid][0];
    adst[0] = ar[0]; adst[1] = ar[1]; adst[2] = ar[2]; adst[3] = ar[3];
    // stage B: fp32 -> bf16 + accumulate row sum-of-squares in fp32
    {
      const float* vv = (const float*)br;
      union { unsigned short s[8]; uint4 v; } h0, h1;
      #pragma unroll
      for (int e = 0; e < 8; ++e) h0.s[e] = f2bf(vv[e]);
      #pragma unroll
      for (int e = 0; e < 8; ++e) h1.s[e] = f2bf(vv[8 + e]);
      #pragma unroll
      for (int e = 0; e < 16; ++e) ssq = fmaf(vv[e], vv[e], ssq);
      *(uint4*)&sm.g.Bs[brow][bh * 16]     = h0.v;
      *(uint4*)&sm.g.Bs[brow][bh * 16 + 8] = h1.v;
    }
    __syncthreads();
    // prefetch next kstep's globals into regs (overlaps with MFMA below)
    if (ks + 1 < KSTEPS) {
      const uint4* ap = aptr + (ks + 1) * 1024;
      ar[0] = ap[0]; ar[1] = ap[1]; ar[2] = ap[2]; ar[3] = ap[3];
      if (bvalid) {
        const float4* bp = bptr + (ks + 1) * 8;
        br[0] = bp[0]; br[1] = bp[1]; br[2] = bp[2]; br[3] = bp[3];
      }
    }
    // MFMA: wave w owns m-frags {2w,2w+1}, all 4 n-frags
    #pragma unroll
    for (int s = 0; s < 2; ++s) {
      bfrag af[2], bfr[4];
      #pragma unroll
      for (int i = 0; i < 2; ++i)
        af[i] = *(const bfrag*)&sm.g.As[(2 * w + i) * 32 + lrow][s * 16 + lhalf * 8];
      #pragma unroll
      for (int j = 0; j < 4; ++j)
        bfr[j] = *(const bfrag*)&sm.g.Bs[j * 32 + lrow][s * 16 + lhalf * 8];
      #pragma unroll
      for (int i = 0; i < 2; ++i)
        #pragma unroll
        for (int j = 0; j < 4; ++j)
          acc[i][j] = __builtin_amdgcn_mfma_f32_32x32x16_bf16(af[i], bfr[j], acc[i][j], 0, 0, 0);
    }
  }

  // norm_all for this WG's 128 rows (pair-reduce halves)
  ssq += __shfl_xor(ssq, 1);
  if (bh == 0) norms[brow] = fmaxf(ssq, 1e-8f);

  // per-row approx top-8 over this WG's 128 columns (4 passes of 32 cols)
  float tv[8]; int ti[8];
  #pragma unroll
  for (int q = 0; q < 8; ++q) { tv[q] = NEG_INF; ti[q] = 0; }

  #pragma unroll
  for (int p = 0; p < 4; ++p) {
    __syncthreads();   // pass 0: also guarantees MFMA reads done + norms visible
    {
      const int   ugc = n0 + 32 * p + lrow;
      const float inv = 1.0f / norms[32 * p + lrow];
      #pragma unroll
      for (int i = 0; i < 2; ++i)
        #pragma unroll
        for (int r = 0; r < 16; ++r) {
          int mrow = 32 * i + (r & 3) + 8 * (r >> 2) + 4 * lhalf;  // verified C/D map (m74/m101)
          float v = (ugc < N_USERS) ? acc[i][p][r] * inv : NEG_INF;
          sm.dump[w][mrow][lrow] = v;
        }
    }
    __syncthreads();
    for (int c = 0; c < 32; ++c) {
      float v = sm.dump[w][lane][c];
      int ci = n0 + 32 * p + c;
      #pragma unroll
      for (int q = 0; q < 8; ++q) {
        bool gt = v > tv[q];
        float ov = tv[q]; int oi = ti[q];
        tv[q] = gt ? v : ov; ti[q] = gt ? ci : oi;
        v = gt ? ov : v;     ci = gt ? oi : ci;
      }
    }
  }

  float2* dst = wstop + ((size_t)blockIdx.x * 256 + tid) * 8;   // b-row == tid
  #pragma unroll
  for (int q = 0; q < 8; ++q) dst[q] = make_float2(tv[q], __int_as_float(ti[q]));
}

// ---------------- Kernel 3: merge 391x8 candidates -> top-32 per row
__global__ __launch_bounds__(64) void merge_topk(
    const float2* __restrict__ wstop, int* __restrict__ cand) {
  const int b = blockIdx.x, l = threadIdx.x;
  float tv[8]; int ti[8];
  #pragma unroll
  for (int q = 0; q < 8; ++q) { tv[q] = NEG_INF; ti[q] = 0; }
  for (int c = l; c < NWG * 8; c += 64) {
    int wg = c >> 3, q = c & 7;
    float2 e = wstop[((size_t)wg * 256 + b) * 8 + q];
    float v = e.x; int ci = __float_as_int(e.y);
    #pragma unroll
    for (int q2 = 0; q2 < 8; ++q2) {
      bool gt = v > tv[q2];
      float ov = tv[q2]; int oi = ti[q2];
      tv[q2] = gt ? v : ov; ti[q2] = gt ? ci : oi;
      v = gt ? ov : v;      ci = gt ? oi : ci;
    }
  }
  __shared__ float sv[512];
  __shared__ int   si[512];
  #pragma unroll
  for (int q = 0; q < 8; ++q) { sv[l * 8 + q] = tv[q]; si[l * 8 + q] = ti[q]; }
  __syncthreads();
  if (l == 0) {
    float bv[32]; int bi[32];
    #pragma unroll
    for (int q = 0; q < 32; ++q) { bv[q] = NEG_INF; bi[q] = 0; }
    for (int n = 0; n < 512; ++n) {
      float v = sv[n];
      if (v > bv[31]) {
        int ci = si[n];
        #pragma unroll
        for (int q = 0; q < 32; ++q) {
          bool gt = v > bv[q];
          float ov = bv[q]; int oi = bi[q];
          bv[q] = gt ? v : ov; bi[q] = gt ? ci : oi;
          v = gt ? ov : v;     ci = gt ? oi : ci;
        }
      }
    }
    #pragma unroll
    for (int q = 0; q < 32; ++q) cand[b * 32 + q] = bi[q];
  }
}

// ---------------- Kernel 4: exact fp64 rescore of the 32 candidates per row
__global__ __launch_bounds__(64) void rescore(
    const float* __restrict__ F, const int* __restrict__ uids,
    const int* __restrict__ cand, double* __restrict__ simx) {
  const int pr = blockIdx.x;           // b*32 + q
  const int b  = pr >> 5;
  const int ci = cand[pr];
  const float* fa = F + (size_t)uids[b] * N_ITEMS;
  const float* fc = F + (size_t)ci * N_ITEMS;
  double dot = 0.0, ss = 0.0;
  for (int k = threadIdx.x * 4; k < N_ITEMS; k += 256) {
    float4 a = *(const float4*)(fa + k);
    float4 c = *(const float4*)(fc + k);
    dot += (double)a.x * c.x + (double)a.y * c.y + (double)a.z * c.z + (double)a.w * c.w;
    ss  += (double)c.x * c.x + (double)c.y * c.y + (double)c.z * c.z + (double)c.w * c.w;
  }
  #pragma unroll
  for (int off = 32; off > 0; off >>= 1) {
    dot += __shfl_down(dot, off);
    ss  += __shfl_down(ss, off);
  }
  // norm_users cancels in the weight normalization -> rank/weight by dot/norm_all only
  if (threadIdx.x == 0) simx[pr] = dot / fmax(ss, 1e-8);
}

// ---------------- Kernel 5: exact top-10, weights, weighted neighbor sum
__global__ __launch_bounds__(256) void finalize(
    const float* __restrict__ F, const int* __restrict__ cand,
    const double* __restrict__ simx, float* __restrict__ out) {
  const int b = blockIdx.x;
  __shared__ float wsh[10];
  __shared__ int   ish[10];
  if (threadIdx.x == 0) {
    double bv[10]; int bi[10];
    #pragma unroll
    for (int q = 0; q < 10; ++q) { bv[q] = -1.0e300; bi[q] = 0; }
    for (int n = 0; n < 32; ++n) {
      double v = simx[b * 32 + n];
      int ci = cand[b * 32 + n];
      #pragma unroll
      for (int q = 0; q < 10; ++q) {
        bool gt = v > bv[q];
        double ov = bv[q]; int oi = bi[q];
        bv[q] = gt ? v : ov; bi[q] = gt ? ci : oi;
        v = gt ? ov : v;     ci = gt ? oi : ci;
      }
    }
    double s = 0.0;
    #pragma unroll
    for (int q = 0; q < 10; ++q) s += bv[q];
    #pragma unroll
    for (int q = 0; q < 10; ++q) { wsh[q] = (float)(bv[q] / s); ish[q] = bi[q]; }
  }
  __syncthreads();
  float wr[10]; size_t ro[10];
  #pragma unroll
  for (int q = 0; q < 10; ++q) { wr[q] = wsh[q]; ro[q] = (size_t)ish[q] * N_ITEMS; }
  for (int i = threadIdx.x; i < N_ITEMS; i += 256) {
    float a = 0.f;
    #pragma unroll
    for (int q = 0; q < 10; ++q) a = fmaf(wr[q], F[ro[q] + i], a);
    out[b * N_ITEMS + i] = a;
  }
}

extern "C" void kernel_launch(void* const* d_in, const int* in_sizes, int n_in,
                              void* d_out, int out_size, void* d_ws, size_t ws_size,
                              hipStream_t stream) {
  const float* F    = (const float*)d_in[0];
  const int*   uids = (const int*)d_in[1];   // num_neighbors (d_in[2]) is fixed at 10
  float* out = (float*)d_out;
  char*  ws  = (char*)d_ws;

  // workspace layout (~8.6 MB total)
  unsigned short* apack = (unsigned short*)ws;                       // 2,048,000 B
  float2* wstop = (float2*)(ws + 2097152);                           // 6,406,144 B
  int*    cand  = (int*)(ws + 2097152 + 6406144);                    //    32,768 B
  double* simx  = (double*)(ws + 2097152 + 6406144 + 32768);         //    65,536 B

  prep_pack<<<dim3(BATCH), dim3(256), 0, stream>>>(F, uids, apack);
  gemm_topk<<<dim3(NWG),   dim3(256), 0, stream>>>(F, apack, wstop);
  merge_topk<<<dim3(BATCH), dim3(64), 0, stream>>>(wstop, cand);
  rescore<<<dim3(BATCH * 32), dim3(64), 0, stream>>>(F, uids, cand, simx);
  finalize<<<dim3(BATCH), dim3(256), 0, stream>>>(F, cand, simx, out);
}